// Round 10
// baseline (180.400 us; speedup 1.0000x reference)
//
#include <hip/hip_runtime.h>
#include <math.h>

static constexpr int CH_IN  = 128;
static constexpr int CH_HID = 128;
static constexpr int CH_OUT = 64;
static constexpr int NSH    = 8;     // histogram shards (~XCD count)

typedef __attribute__((ext_vector_type(8))) short bf16x8;
typedef __attribute__((ext_vector_type(4))) float f32x4;

// ---------- bf16 helpers (RNE pack, cheap unpack) ----------

__device__ __forceinline__ float bf2f(unsigned short u) {
    return __uint_as_float(((unsigned int)u) << 16);
}
__device__ __forceinline__ unsigned short f2bf(float f) {
    unsigned int u = __float_as_uint(f);
    u = (u + 0x7fffu + ((u >> 16) & 1u)) >> 16;   // round-to-nearest-even
    return (unsigned short)u;
}
__device__ __forceinline__ unsigned int pack2(float lo, float hi) {
    return (unsigned int)f2bf(lo) | ((unsigned int)f2bf(hi) << 16);
}
__device__ __forceinline__ void unpack2(unsigned int u, float& lo, float& hi) {
    lo = __uint_as_float(u << 16);
    hi = __uint_as_float(u & 0xffff0000u);
}
__device__ __forceinline__ unsigned int relu2(unsigned int u) {
    unsigned int m = 0;
    if (!(u & 0x8000u)) m |= 0xffffu;
    if (!(u & 0x80000000u)) m |= 0xffff0000u;
    return u & m;
}

// ---------- fused setup: zero shard counters + transpose/convert both weights ----------

__global__ void k_setup(int* __restrict__ cnt_s, int zn,
                        const float* __restrict__ W1, unsigned short* __restrict__ w1t,
                        const float* __restrict__ W2, unsigned short* __restrict__ w2t) {
    int i = blockIdx.x * blockDim.x + threadIdx.x;
    if (i < zn) { cnt_s[i] = 0; return; }
    int j = i - zn;
    if (j < CH_HID * 128) {
        int c = j >> 7, k = j & 127;
        w1t[(size_t)c * 128 + k] = f2bf(W1[(size_t)k * CH_HID + c]);
        return;
    }
    j -= CH_HID * 128;
    if (j < CH_OUT * 128) {
        int c = j >> 7, k = j & 127;
        w2t[(size_t)c * 128 + k] = f2bf(W2[(size_t)k * CH_OUT + c]);
    }
}

// ---------- MFMA GEMM body (shared by fat kernel and k_gemm_mfma) ----------

template<int COLS, bool RELU_IN, typename TIN>
__device__ __forceinline__ void gemm_body(const TIN* __restrict__ X,
                                          const unsigned short* __restrict__ Wt,
                                          unsigned short* __restrict__ H, int N, int blk) {
    constexpr int NCT = COLS / 16;
    __shared__ unsigned short As[64 * 136];
    const int tid = threadIdx.x;
    const int lane = tid & 63, wv = tid >> 6;
    const int row0 = blk * 64;

    if constexpr (sizeof(TIN) == 4) {
        #pragma unroll
        for (int j = 0; j < 8; ++j) {
            int f = j * 256 + tid;
            int row = f >> 5, col = (f & 31) * 4;
            float4 v = make_float4(0.f, 0.f, 0.f, 0.f);
            if (row0 + row < N)
                v = *reinterpret_cast<const float4*>((const float*)X + (size_t)(row0 + row) * CH_IN + col);
            uint2 p;
            p.x = pack2(v.x, v.y);
            p.y = pack2(v.z, v.w);
            *reinterpret_cast<uint2*>(&As[row * 136 + col]) = p;
        }
    } else {
        #pragma unroll
        for (int j = 0; j < 4; ++j) {
            int f = j * 256 + tid;
            int row = f >> 4, col = (f & 15) * 8;
            uint4 v = make_uint4(0u, 0u, 0u, 0u);
            if (row0 + row < N) {
                v = *reinterpret_cast<const uint4*>((const unsigned short*)X + (size_t)(row0 + row) * CH_IN + col);
                if (RELU_IN) {
                    v.x = relu2(v.x); v.y = relu2(v.y);
                    v.z = relu2(v.z); v.w = relu2(v.w);
                }
            }
            *reinterpret_cast<uint4*>(&As[row * 136 + col]) = v;
        }
    }
    __syncthreads();

    const int rw0  = wv * 16;
    const int arow = rw0 + (lane & 15);
    const int kgrp = (lane >> 4) * 8;
    f32x4 acc[NCT];
    #pragma unroll
    for (int c = 0; c < NCT; ++c) acc[c] = f32x4{0.f, 0.f, 0.f, 0.f};

    #pragma unroll
    for (int kk = 0; kk < 4; ++kk) {
        bf16x8 af = *reinterpret_cast<const bf16x8*>(&As[arow * 136 + kk * 32 + kgrp]);
        #pragma unroll
        for (int ct = 0; ct < NCT; ++ct) {
            bf16x8 bf = *reinterpret_cast<const bf16x8*>(
                Wt + (size_t)(ct * 16 + (lane & 15)) * 128 + kk * 32 + kgrp);
            acc[ct] = __builtin_amdgcn_mfma_f32_16x16x32_bf16(af, bf, acc[ct], 0, 0, 0);
        }
    }

    const int orow0 = row0 + rw0 + (lane >> 4) * 4;
    const int ocol  = lane & 15;
    #pragma unroll
    for (int ct = 0; ct < NCT; ++ct) {
        #pragma unroll
        for (int r = 0; r < 4; ++r) {
            int row = orow0 + r;
            if (row < N) H[(size_t)row * COLS + ct * 16 + ocol] = f2bf(acc[ct][r]);
        }
    }
}

// ---------- fat kernel: GEMM1 (blocks < nbg) concurrent with sharded histogram ----------

__global__ void __launch_bounds__(256) k_fat(
        const float* __restrict__ x, const unsigned short* __restrict__ w1t,
        unsigned short* __restrict__ h1, int N, int nbg,
        const int* __restrict__ ei, int* __restrict__ cnt_s, int* __restrict__ eord, int E) {
    if ((int)blockIdx.x < nbg) {
        gemm_body<CH_HID, false, float>(x, w1t, h1, N, blockIdx.x);
    } else {
        int e = (blockIdx.x - nbg) * 256 + threadIdx.x;
        if (e < E) {
            int sh = (e >> 8) & (NSH - 1);
            eord[e] = atomicAdd(&cnt_s[sh * N + ei[E + e]], 1);
        }
    }
}

// standalone GEMM (layer 2)
template<int COLS, bool RELU_IN, typename TIN>
__global__ void __launch_bounds__(256) k_gemm_mfma(const TIN* __restrict__ X,
        const unsigned short* __restrict__ Wt, unsigned short* __restrict__ H, int N) {
    gemm_body<COLS, RELU_IN, TIN>(X, Wt, H, N, blockIdx.x);
}

// ---------- merged: per-node shard prefix + block-level inclusive scan ----------

__global__ void k_shardscan_pre(int* __restrict__ cnt_s, int* __restrict__ rowptr,
                                int* __restrict__ bsum, int N) {
    __shared__ int wtot[4];
    const int tid = threadIdx.x, lane = tid & 63, wid = tid >> 6;
    const int d = blockIdx.x * 256 + tid;
    int run = 0;
    if (d < N) {
        #pragma unroll
        for (int s = 0; s < NSH; ++s) {
            int idx = s * N + d;
            int c = cnt_s[idx];
            cnt_s[idx] = run;
            run += c;
        }
    }
    int s = run;
    #pragma unroll
    for (int off = 1; off < 64; off <<= 1) {
        int t = __shfl_up(s, off, 64);
        if (lane >= off) s += t;
    }
    if (lane == 63) wtot[wid] = s;
    __syncthreads();
    int woff = 0;
    for (int j = 0; j < wid; ++j) woff += wtot[j];
    s += woff;
    if (d < N) rowptr[d + 1] = s;
    if (tid == 255) bsum[blockIdx.x] = s;
}

// adds sum(bsum[0..bid-1]) to this block's 256 rowptr entries (nb <= 256)
__global__ void k_scan_add(int* __restrict__ rowptr, const int* __restrict__ bsum, int N) {
    __shared__ int wsum[4];
    __shared__ int off_s;
    const int tid = threadIdx.x, lane = tid & 63, wid = tid >> 6;
    const int bid = blockIdx.x;
    int v = (tid < bid) ? bsum[tid] : 0;
    #pragma unroll
    for (int off = 32; off > 0; off >>= 1) v += __shfl_xor(v, off, 64);
    if (lane == 0) wsum[wid] = v;
    __syncthreads();
    if (tid == 0) off_s = wsum[0] + wsum[1] + wsum[2] + wsum[3];
    __syncthreads();
    int i = bid * 256 + tid;
    if (i < N) {
        rowptr[i + 1] += off_s;
        if (i == 0) rowptr[0] = 0;
    }
}

// atomic-free fill: pos = rowptr[d] + shard-prefix + ordinal; epack = {src, bits(w)}
__global__ void k_fill(const int* __restrict__ ei, const float* __restrict__ w,
                       const int* __restrict__ eord, const int* __restrict__ rowptr,
                       const int* __restrict__ cnt_s, int2* __restrict__ epack, int E, int N) {
    int e = blockIdx.x * blockDim.x + threadIdx.x;
    if (e < E) {
        int d = ei[E + e];
        int sh = (e >> 8) & (NSH - 1);
        int pos = rowptr[d] + cnt_s[sh * N + d] + eord[e];
        epack[pos] = make_int2(ei[e], __float_as_int(w[e]));
    }
}

// dinv[n] = rsqrt(1 + sum of row weights); wave per node, coalesced
__global__ void k_degdinv(const int* __restrict__ rowptr, const int2* __restrict__ epack,
                          float* __restrict__ dinv, int N) {
    const int node = (blockIdx.x * blockDim.x + threadIdx.x) >> 6;
    const int lane = threadIdx.x & 63;
    if (node >= N) return;
    const int beg = rowptr[node], end = rowptr[node + 1];
    float s = 0.f;
    for (int i = beg + lane; i < end; i += 64) s += __int_as_float(epack[i].y);
    #pragma unroll
    for (int off = 32; off > 0; off >>= 1) s += __shfl_xor(s, off, 64);
    if (lane == 0) dinv[node] = rsqrtf(1.0f + s);
}

// ---------- CSR aggregation, 16B/lane gathers ----------
// out[n][:] = b + h[n]*dd^2 + dd * sum_e h[src_e] * (w_e * dinv[src_e])
// agg128: lane = 16*g + ci (g: edge subgroup 0..3, ci: channel block 0..15).
// One load instr gathers 4 edge-rows x 256B = 1KB. Padded lanes (idx>=m): s=0, nm=0.

__global__ void k_agg128(const int* __restrict__ rowptr, const int2* __restrict__ epack,
                         const float* __restrict__ dinv, const unsigned short* __restrict__ h,
                         const float* __restrict__ b, unsigned short* __restrict__ out, int N) {
    const int node = (blockIdx.x * blockDim.x + threadIdx.x) >> 6;
    const int lane = threadIdx.x & 63;
    if (node >= N) return;
    const int beg = rowptr[node], end = rowptr[node + 1];
    const float dd = dinv[node];
    const int g  = lane >> 4;              // 0..3
    const int ci = lane & 15;              // channels [8ci, 8ci+8)
    const uint4* hp = (const uint4*)h;     // 16 uint4 per row

    float acc[8];
    #pragma unroll
    for (int q = 0; q < 8; ++q) acc[q] = 0.f;

    for (int i0 = beg; i0 < end; i0 += 64) {
        const int m = min(64, end - i0);
        int s_l = 0; float nm_l = 0.f;
        if (lane < m) {
            int2 p = epack[i0 + lane];
            s_l = p.x;
            nm_l = __int_as_float(p.y) * dinv[p.x];   // dinv: 200KB, L2-hit
        }
        for (int j = 0; j < m; j += 32) {
            #pragma unroll
            for (int k = 0; k < 8; ++k) {
                int idx = j + 4 * k + g;               // 0..63
                int   s  = __shfl(s_l, idx, 64);
                float nm = __shfl(nm_l, idx, 64);
                uint4 v = hp[(size_t)s * 16 + ci];
                float lo, hi;
                unpack2(v.x, lo, hi); acc[0] = fmaf(lo, nm, acc[0]); acc[1] = fmaf(hi, nm, acc[1]);
                unpack2(v.y, lo, hi); acc[2] = fmaf(lo, nm, acc[2]); acc[3] = fmaf(hi, nm, acc[3]);
                unpack2(v.z, lo, hi); acc[4] = fmaf(lo, nm, acc[4]); acc[5] = fmaf(hi, nm, acc[5]);
                unpack2(v.w, lo, hi); acc[6] = fmaf(lo, nm, acc[6]); acc[7] = fmaf(hi, nm, acc[7]);
            }
        }
    }
    // combine 4 edge subgroups (lane bits 4,5)
    #pragma unroll
    for (int q = 0; q < 8; ++q) {
        acc[q] += __shfl_xor(acc[q], 16, 64);
        acc[q] += __shfl_xor(acc[q], 32, 64);
    }
    // self + bias, write by g==0 lanes (16 x uint4 = 256B per node)
    uint4 hv = hp[(size_t)node * 16 + ci];
    float hn[8];
    unpack2(hv.x, hn[0], hn[1]); unpack2(hv.y, hn[2], hn[3]);
    unpack2(hv.z, hn[4], hn[5]); unpack2(hv.w, hn[6], hn[7]);
    float4 b0 = *reinterpret_cast<const float4*>(b + 8 * ci);
    float4 b1v = *reinterpret_cast<const float4*>(b + 8 * ci + 4);
    const float bb[8] = {b0.x, b0.y, b0.z, b0.w, b1v.x, b1v.y, b1v.z, b1v.w};
    float res[8];
    #pragma unroll
    for (int q = 0; q < 8; ++q)
        res[q] = fmaf(acc[q], dd, fmaf(hn[q], dd * dd, bb[q]));
    if (g == 0) {
        uint4 o;
        o.x = pack2(res[0], res[1]); o.y = pack2(res[2], res[3]);
        o.z = pack2(res[4], res[5]); o.w = pack2(res[6], res[7]);
        ((uint4*)out)[(size_t)node * 16 + ci] = o;
    }
}

// agg64: lane = 8*g + ci (g: 0..7, ci: 0..7, channels [8ci,8ci+8)).
// One load instr gathers 8 edge-rows x 128B = 1KB; whole 64-edge chunk = 1 round.
// Fused log_softmax; fp32 out (d_out).
__global__ void k_agg64(const int* __restrict__ rowptr, const int2* __restrict__ epack,
                        const float* __restrict__ dinv, const unsigned short* __restrict__ h,
                        const float* __restrict__ b, float* __restrict__ out, int N) {
    const int node = (blockIdx.x * blockDim.x + threadIdx.x) >> 6;
    const int lane = threadIdx.x & 63;
    if (node >= N) return;
    const int beg = rowptr[node], end = rowptr[node + 1];
    const float dd = dinv[node];
    const int g  = lane >> 3;              // 0..7
    const int ci = lane & 7;               // channels [8ci, 8ci+8)
    const uint4* hp = (const uint4*)h;     // 8 uint4 per row

    float acc[8];
    #pragma unroll
    for (int q = 0; q < 8; ++q) acc[q] = 0.f;

    for (int i0 = beg; i0 < end; i0 += 64) {
        const int m = min(64, end - i0);
        int s_l = 0; float nm_l = 0.f;
        if (lane < m) {
            int2 p = epack[i0 + lane];
            s_l = p.x;
            nm_l = __int_as_float(p.y) * dinv[p.x];
        }
        #pragma unroll
        for (int k = 0; k < 8; ++k) {
            int idx = 8 * k + g;                        // 0..63
            int   s  = __shfl(s_l, idx, 64);
            float nm = __shfl(nm_l, idx, 64);
            uint4 v = hp[(size_t)s * 8 + ci];
            float lo, hi;
            unpack2(v.x, lo, hi); acc[0] = fmaf(lo, nm, acc[0]); acc[1] = fmaf(hi, nm, acc[1]);
            unpack2(v.y, lo, hi); acc[2] = fmaf(lo, nm, acc[2]); acc[3] = fmaf(hi, nm, acc[3]);
            unpack2(v.z, lo, hi); acc[4] = fmaf(lo, nm, acc[4]); acc[5] = fmaf(hi, nm, acc[5]);
            unpack2(v.w, lo, hi); acc[6] = fmaf(lo, nm, acc[6]); acc[7] = fmaf(hi, nm, acc[7]);
        }
    }
    // combine 8 edge subgroups (lane bits 3,4,5)
    #pragma unroll
    for (int q = 0; q < 8; ++q) {
        acc[q] += __shfl_xor(acc[q], 8, 64);
        acc[q] += __shfl_xor(acc[q], 16, 64);
        acc[q] += __shfl_xor(acc[q], 32, 64);
    }
    // self + bias
    uint4 hv = hp[(size_t)node * 8 + ci];
    float hn[8];
    unpack2(hv.x, hn[0], hn[1]); unpack2(hv.y, hn[2], hn[3]);
    unpack2(hv.z, hn[4], hn[5]); unpack2(hv.w, hn[6], hn[7]);
    float4 b0 = *reinterpret_cast<const float4*>(b + 8 * ci);
    float4 b1v = *reinterpret_cast<const float4*>(b + 8 * ci + 4);
    const float bb[8] = {b0.x, b0.y, b0.z, b0.w, b1v.x, b1v.y, b1v.z, b1v.w};
    float res[8];
    #pragma unroll
    for (int q = 0; q < 8; ++q)
        res[q] = fmaf(acc[q], dd, fmaf(hn[q], dd * dd, bb[q]));

    // log_softmax over 64 channels: local 8 -> cross-ci (lane bits 0,1,2)
    float mx = res[0];
    #pragma unroll
    for (int q = 1; q < 8; ++q) mx = fmaxf(mx, res[q]);
    mx = fmaxf(mx, __shfl_xor(mx, 1, 64));
    mx = fmaxf(mx, __shfl_xor(mx, 2, 64));
    mx = fmaxf(mx, __shfl_xor(mx, 4, 64));
    float sm = 0.f;
    #pragma unroll
    for (int q = 0; q < 8; ++q) sm += expf(res[q] - mx);
    sm += __shfl_xor(sm, 1, 64);
    sm += __shfl_xor(sm, 2, 64);
    sm += __shfl_xor(sm, 4, 64);
    float lse = mx + logf(sm);
    if (g == 0) {
        float4 o0 = make_float4(res[0] - lse, res[1] - lse, res[2] - lse, res[3] - lse);
        float4 o1 = make_float4(res[4] - lse, res[5] - lse, res[6] - lse, res[7] - lse);
        *reinterpret_cast<float4*>(out + (size_t)node * 64 + 8 * ci)     = o0;
        *reinterpret_cast<float4*>(out + (size_t)node * 64 + 8 * ci + 4) = o1;
    }
}

extern "C" void kernel_launch(void* const* d_in, const int* in_sizes, int n_in,
                              void* d_out, int out_size, void* d_ws, size_t ws_size,
                              hipStream_t stream) {
    const float* x  = (const float*)d_in[0];
    const int*   ei = (const int*)d_in[1];     // [2,E]: src = ei[e], dst = ei[E+e]
    const float* w  = (const float*)d_in[2];
    const float* W1 = (const float*)d_in[3];
    const float* b1 = (const float*)d_in[4];
    const float* W2 = (const float*)d_in[5];
    const float* b2 = (const float*)d_in[6];
    float* out = (float*)d_out;

    const int N = in_sizes[0] / CH_IN;
    const int E = in_sizes[2];
    const int NB = (N + 255) / 256;            // scan blocks (<= 256)

    // workspace carve (float units; epack 8B-aligned, bf16 arrays 16B-aligned)
    float* ws0   = (float*)d_ws;
    float* ws    = ws0;
    float* dinv  = ws;               ws += N;
    int*   rowptr= (int*)ws;         ws += (N + 2);
    int*   bsum  = (int*)ws;         ws += 256;
    int*   cnt_s = (int*)ws;         ws += (size_t)NSH * N;
    int*   eord  = (int*)ws;         ws += E;
    int2*  epack = (int2*)ws;        ws += (size_t)2 * E;
    { size_t off = (size_t)(ws - ws0) & 3; if (off) ws += 4 - off; }
    unsigned short* w1t  = (unsigned short*)ws;  ws += (size_t)CH_HID * 128 / 2;
    unsigned short* w2t  = (unsigned short*)ws;  ws += (size_t)CH_OUT * 128 / 2;
    unsigned short* h1   = (unsigned short*)ws;  ws += (size_t)N * CH_HID / 2;
    unsigned short* out1 = (unsigned short*)ws;  ws += (size_t)N * CH_HID / 2;
    unsigned short* h2   = (unsigned short*)ws;  ws += (size_t)N * CH_OUT / 2;

    const int B = 256;
    const int setup_total = NSH * N + CH_HID * 128 + CH_OUT * 128;

    // 0) fused setup: zero shard counters + both weight transposes
    k_setup<<<(setup_total + B - 1) / B, B, 0, stream>>>(cnt_s, NSH * N, W1, w1t, W2, w2t);

    // 1) fat kernel: GEMM1 co-scheduled with sharded histogram
    {
        const int nbg = (N + 63) / 64;
        const int nbh = (E + B - 1) / B;
        k_fat<<<nbg + nbh, B, 0, stream>>>(x, w1t, h1, N, nbg, ei, cnt_s, eord, E);
    }

    // 2) shard prefix + block scan; cross-block add; atomic-free fill; degree
    k_shardscan_pre<<<NB, 256, 0, stream>>>(cnt_s, rowptr, bsum, N);
    k_scan_add<<<NB, 256, 0, stream>>>(rowptr, bsum, N);
    k_fill<<<(E + B - 1) / B, B, 0, stream>>>(ei, w, eord, rowptr, cnt_s, epack, E, N);
    k_degdinv<<<(N * 64 + B - 1) / B, B, 0, stream>>>(rowptr, epack, dinv, N);

    // 3) out1 = b1 + self + neighbor aggregate (16B/lane gathers)
    k_agg128<<<(N * 64 + B - 1) / B, B, 0, stream>>>(rowptr, epack, dinv, h1, b1, out1, N);

    // 4) h2 = relu(out1) @ W2  (bf16 in w/ fused relu, MFMA, bf16 out)
    k_gemm_mfma<CH_OUT, true, unsigned short><<<(N + 63) / 64, 256, 0, stream>>>(out1, w2t, h2, N);

    // 5) out = log_softmax(b2 + self + aggregate), fused, fp32 into d_out
    k_agg64<<<(N * 64 + B - 1) / B, B, 0, stream>>>(rowptr, epack, dinv, h2, b2, out, N);
}

// Round 11
// 162.056 us; speedup vs baseline: 1.1132x; 1.1132x over previous
//
#include <hip/hip_runtime.h>
#include <math.h>

static constexpr int CH_IN  = 128;
static constexpr int CH_HID = 128;
static constexpr int CH_OUT = 64;
static constexpr int NSH    = 8;     // histogram shards (~XCD count)

typedef __attribute__((ext_vector_type(8))) short bf16x8;
typedef __attribute__((ext_vector_type(4))) float f32x4;

// ---------- bf16 helpers (RNE pack, cheap unpack) ----------

__device__ __forceinline__ float bf2f(unsigned short u) {
    return __uint_as_float(((unsigned int)u) << 16);
}
__device__ __forceinline__ unsigned short f2bf(float f) {
    unsigned int u = __float_as_uint(f);
    u = (u + 0x7fffu + ((u >> 16) & 1u)) >> 16;   // round-to-nearest-even
    return (unsigned short)u;
}
__device__ __forceinline__ unsigned int pack2(float lo, float hi) {
    return (unsigned int)f2bf(lo) | ((unsigned int)f2bf(hi) << 16);
}
__device__ __forceinline__ void unpack2(unsigned int u, float& lo, float& hi) {
    lo = __uint_as_float(u << 16);
    hi = __uint_as_float(u & 0xffff0000u);
}
__device__ __forceinline__ unsigned int relu2(unsigned int u) {
    unsigned int m = 0;
    if (!(u & 0x8000u)) m |= 0xffffu;
    if (!(u & 0x80000000u)) m |= 0xffff0000u;
    return u & m;
}

// gather one 16B row-segment (8 bf16 ch) and accumulate into acc[0..7]
__device__ __forceinline__ void gacc(const uint4* __restrict__ hp, int stride, int ci,
                                     int s, float nm, float* acc) {
    uint4 v = hp[(size_t)s * stride + ci];
    float lo, hi;
    unpack2(v.x, lo, hi); acc[0] = fmaf(lo, nm, acc[0]); acc[1] = fmaf(hi, nm, acc[1]);
    unpack2(v.y, lo, hi); acc[2] = fmaf(lo, nm, acc[2]); acc[3] = fmaf(hi, nm, acc[3]);
    unpack2(v.z, lo, hi); acc[4] = fmaf(lo, nm, acc[4]); acc[5] = fmaf(hi, nm, acc[5]);
    unpack2(v.w, lo, hi); acc[6] = fmaf(lo, nm, acc[6]); acc[7] = fmaf(hi, nm, acc[7]);
}

// ---------- fused setup: zero shard counters + transpose/convert both weights ----------

__global__ void k_setup(int* __restrict__ cnt_s, int zn,
                        const float* __restrict__ W1, unsigned short* __restrict__ w1t,
                        const float* __restrict__ W2, unsigned short* __restrict__ w2t) {
    int i = blockIdx.x * blockDim.x + threadIdx.x;
    if (i < zn) { cnt_s[i] = 0; return; }
    int j = i - zn;
    if (j < CH_HID * 128) {
        int c = j >> 7, k = j & 127;
        w1t[(size_t)c * 128 + k] = f2bf(W1[(size_t)k * CH_HID + c]);
        return;
    }
    j -= CH_HID * 128;
    if (j < CH_OUT * 128) {
        int c = j >> 7, k = j & 127;
        w2t[(size_t)c * 128 + k] = f2bf(W2[(size_t)k * CH_OUT + c]);
    }
}

// ---------- MFMA GEMM body (shared by fat kernel and k_gemm_mfma) ----------

template<int COLS, bool RELU_IN, typename TIN>
__device__ __forceinline__ void gemm_body(const TIN* __restrict__ X,
                                          const unsigned short* __restrict__ Wt,
                                          unsigned short* __restrict__ H, int N, int blk) {
    constexpr int NCT = COLS / 16;
    __shared__ unsigned short As[64 * 136];
    const int tid = threadIdx.x;
    const int lane = tid & 63, wv = tid >> 6;
    const int row0 = blk * 64;

    if constexpr (sizeof(TIN) == 4) {
        #pragma unroll
        for (int j = 0; j < 8; ++j) {
            int f = j * 256 + tid;
            int row = f >> 5, col = (f & 31) * 4;
            float4 v = make_float4(0.f, 0.f, 0.f, 0.f);
            if (row0 + row < N)
                v = *reinterpret_cast<const float4*>((const float*)X + (size_t)(row0 + row) * CH_IN + col);
            uint2 p;
            p.x = pack2(v.x, v.y);
            p.y = pack2(v.z, v.w);
            *reinterpret_cast<uint2*>(&As[row * 136 + col]) = p;
        }
    } else {
        #pragma unroll
        for (int j = 0; j < 4; ++j) {
            int f = j * 256 + tid;
            int row = f >> 4, col = (f & 15) * 8;
            uint4 v = make_uint4(0u, 0u, 0u, 0u);
            if (row0 + row < N) {
                v = *reinterpret_cast<const uint4*>((const unsigned short*)X + (size_t)(row0 + row) * CH_IN + col);
                if (RELU_IN) {
                    v.x = relu2(v.x); v.y = relu2(v.y);
                    v.z = relu2(v.z); v.w = relu2(v.w);
                }
            }
            *reinterpret_cast<uint4*>(&As[row * 136 + col]) = v;
        }
    }
    __syncthreads();

    const int rw0  = wv * 16;
    const int arow = rw0 + (lane & 15);
    const int kgrp = (lane >> 4) * 8;
    f32x4 acc[NCT];
    #pragma unroll
    for (int c = 0; c < NCT; ++c) acc[c] = f32x4{0.f, 0.f, 0.f, 0.f};

    #pragma unroll
    for (int kk = 0; kk < 4; ++kk) {
        bf16x8 af = *reinterpret_cast<const bf16x8*>(&As[arow * 136 + kk * 32 + kgrp]);
        #pragma unroll
        for (int ct = 0; ct < NCT; ++ct) {
            bf16x8 bf = *reinterpret_cast<const bf16x8*>(
                Wt + (size_t)(ct * 16 + (lane & 15)) * 128 + kk * 32 + kgrp);
            acc[ct] = __builtin_amdgcn_mfma_f32_16x16x32_bf16(af, bf, acc[ct], 0, 0, 0);
        }
    }

    const int orow0 = row0 + rw0 + (lane >> 4) * 4;
    const int ocol  = lane & 15;
    #pragma unroll
    for (int ct = 0; ct < NCT; ++ct) {
        #pragma unroll
        for (int r = 0; r < 4; ++r) {
            int row = orow0 + r;
            if (row < N) H[(size_t)row * COLS + ct * 16 + ocol] = f2bf(acc[ct][r]);
        }
    }
}

// ---------- fat kernel: GEMM1 (blocks < nbg) concurrent with sharded histogram ----------

__global__ void __launch_bounds__(256) k_fat(
        const float* __restrict__ x, const unsigned short* __restrict__ w1t,
        unsigned short* __restrict__ h1, int N, int nbg,
        const int* __restrict__ ei, int* __restrict__ cnt_s, int* __restrict__ eord, int E) {
    if ((int)blockIdx.x < nbg) {
        gemm_body<CH_HID, false, float>(x, w1t, h1, N, blockIdx.x);
    } else {
        int e = (blockIdx.x - nbg) * 256 + threadIdx.x;
        if (e < E) {
            int sh = (e >> 8) & (NSH - 1);
            eord[e] = atomicAdd(&cnt_s[sh * N + ei[E + e]], 1);
        }
    }
}

// standalone GEMM (layer 2)
template<int COLS, bool RELU_IN, typename TIN>
__global__ void __launch_bounds__(256) k_gemm_mfma(const TIN* __restrict__ X,
        const unsigned short* __restrict__ Wt, unsigned short* __restrict__ H, int N) {
    gemm_body<COLS, RELU_IN, TIN>(X, Wt, H, N, blockIdx.x);
}

// ---------- merged: per-node shard prefix + block-level inclusive scan ----------

__global__ void k_shardscan_pre(int* __restrict__ cnt_s, int* __restrict__ rowptr,
                                int* __restrict__ bsum, int N) {
    __shared__ int wtot[4];
    const int tid = threadIdx.x, lane = tid & 63, wid = tid >> 6;
    const int d = blockIdx.x * 256 + tid;
    int run = 0;
    if (d < N) {
        #pragma unroll
        for (int s = 0; s < NSH; ++s) {
            int idx = s * N + d;
            int c = cnt_s[idx];
            cnt_s[idx] = run;
            run += c;
        }
    }
    int s = run;
    #pragma unroll
    for (int off = 1; off < 64; off <<= 1) {
        int t = __shfl_up(s, off, 64);
        if (lane >= off) s += t;
    }
    if (lane == 63) wtot[wid] = s;
    __syncthreads();
    int woff = 0;
    for (int j = 0; j < wid; ++j) woff += wtot[j];
    s += woff;
    if (d < N) rowptr[d + 1] = s;
    if (tid == 255) bsum[blockIdx.x] = s;
}

// adds sum(bsum[0..bid-1]) to this block's 256 rowptr entries (nb <= 256)
__global__ void k_scan_add(int* __restrict__ rowptr, const int* __restrict__ bsum, int N) {
    __shared__ int wsum[4];
    __shared__ int off_s;
    const int tid = threadIdx.x, lane = tid & 63, wid = tid >> 6;
    const int bid = blockIdx.x;
    int v = (tid < bid) ? bsum[tid] : 0;
    #pragma unroll
    for (int off = 32; off > 0; off >>= 1) v += __shfl_xor(v, off, 64);
    if (lane == 0) wsum[wid] = v;
    __syncthreads();
    if (tid == 0) off_s = wsum[0] + wsum[1] + wsum[2] + wsum[3];
    __syncthreads();
    int i = bid * 256 + tid;
    if (i < N) {
        rowptr[i + 1] += off_s;
        if (i == 0) rowptr[0] = 0;
    }
}

// atomic-free fill: pos = rowptr[d] + shard-prefix + ordinal; epack = {src, bits(w)}
__global__ void k_fill(const int* __restrict__ ei, const float* __restrict__ w,
                       const int* __restrict__ eord, const int* __restrict__ rowptr,
                       const int* __restrict__ cnt_s, int2* __restrict__ epack, int E, int N) {
    int e = blockIdx.x * blockDim.x + threadIdx.x;
    if (e < E) {
        int d = ei[E + e];
        int sh = (e >> 8) & (NSH - 1);
        int pos = rowptr[d] + cnt_s[sh * N + d] + eord[e];
        epack[pos] = make_int2(ei[e], __float_as_int(w[e]));
    }
}

// dinv[n] = rsqrt(1 + sum of row weights); wave per node, coalesced
__global__ void k_degdinv(const int* __restrict__ rowptr, const int2* __restrict__ epack,
                          float* __restrict__ dinv, int N) {
    const int node = (blockIdx.x * blockDim.x + threadIdx.x) >> 6;
    const int lane = threadIdx.x & 63;
    if (node >= N) return;
    const int beg = rowptr[node], end = rowptr[node + 1];
    float s = 0.f;
    for (int i = beg + lane; i < end; i += 64) s += __int_as_float(epack[i].y);
    #pragma unroll
    for (int off = 32; off > 0; off >>= 1) s += __shfl_xor(s, off, 64);
    if (lane == 0) dinv[node] = rsqrtf(1.0f + s);
}

// ---------- CSR aggregation, 16B/lane gathers, degree-adaptive rounds ----------
// out[n][:] = b + h[n]*dd^2 + dd * sum_e h[src_e] * (w_e * dinv[src_e])
// agg128: lane = 16*g + ci (g: 0..3, ci: 0..15). Round = 4 edges (1 gather/lane).
// Big step: 16 edges (4 gathers ILP). Tail rounds pad <4 edges (s=0, nm=0).

__global__ void k_agg128(const int* __restrict__ rowptr, const int2* __restrict__ epack,
                         const float* __restrict__ dinv, const unsigned short* __restrict__ h,
                         const float* __restrict__ b, unsigned short* __restrict__ out, int N) {
    const int node = (blockIdx.x * blockDim.x + threadIdx.x) >> 6;
    const int lane = threadIdx.x & 63;
    if (node >= N) return;
    const int beg = rowptr[node], end = rowptr[node + 1];
    const float dd = dinv[node];
    const int g  = lane >> 4;              // 0..3
    const int ci = lane & 15;              // channels [8ci, 8ci+8)
    const uint4* hp = (const uint4*)h;     // 16 uint4 per row

    float acc[8];
    #pragma unroll
    for (int q = 0; q < 8; ++q) acc[q] = 0.f;

    for (int i0 = beg; i0 < end; i0 += 64) {
        const int m = min(64, end - i0);
        int s_l = 0; float nm_l = 0.f;
        if (lane < m) {
            int2 p = epack[i0 + lane];
            s_l = p.x;
            nm_l = __int_as_float(p.y) * dinv[p.x];   // dinv: 200KB, L2-hit
        }
        int j = 0;
        for (; j + 16 <= m; j += 16) {                // 4 gathers in flight
            #pragma unroll
            for (int k = 0; k < 4; ++k) {
                int idx = j + 4 * k + g;
                int   s  = __shfl(s_l, idx, 64);
                float nm = __shfl(nm_l, idx, 64);
                gacc(hp, 16, ci, s, nm, acc);
            }
        }
        for (; j < m; j += 4) {                       // tail: <=3 padded edges/round
            int idx = j + g;                          // may be >= m -> s=0, nm=0
            int   s  = __shfl(s_l, idx, 64);
            float nm = __shfl(nm_l, idx, 64);
            gacc(hp, 16, ci, s, nm, acc);
        }
    }
    // combine 4 edge subgroups (lane bits 4,5)
    #pragma unroll
    for (int q = 0; q < 8; ++q) {
        acc[q] += __shfl_xor(acc[q], 16, 64);
        acc[q] += __shfl_xor(acc[q], 32, 64);
    }
    // self + bias, write by g==0 lanes (16 x uint4 = 256B per node)
    uint4 hv = hp[(size_t)node * 16 + ci];
    float hn[8];
    unpack2(hv.x, hn[0], hn[1]); unpack2(hv.y, hn[2], hn[3]);
    unpack2(hv.z, hn[4], hn[5]); unpack2(hv.w, hn[6], hn[7]);
    float4 b0 = *reinterpret_cast<const float4*>(b + 8 * ci);
    float4 b1v = *reinterpret_cast<const float4*>(b + 8 * ci + 4);
    const float bb[8] = {b0.x, b0.y, b0.z, b0.w, b1v.x, b1v.y, b1v.z, b1v.w};
    float res[8];
    #pragma unroll
    for (int q = 0; q < 8; ++q)
        res[q] = fmaf(acc[q], dd, fmaf(hn[q], dd * dd, bb[q]));
    if (g == 0) {
        uint4 o;
        o.x = pack2(res[0], res[1]); o.y = pack2(res[2], res[3]);
        o.z = pack2(res[4], res[5]); o.w = pack2(res[6], res[7]);
        ((uint4*)out)[(size_t)node * 16 + ci] = o;
    }
}

// agg64: lane = 8*g + ci (g: 0..7, ci: 0..7). Round = 8 edges (1 gather/lane).
// Big step: 32 edges (4 gathers ILP). Tail rounds pad <8 edges.
// Fused log_softmax; fp32 out (d_out).
__global__ void k_agg64(const int* __restrict__ rowptr, const int2* __restrict__ epack,
                        const float* __restrict__ dinv, const unsigned short* __restrict__ h,
                        const float* __restrict__ b, float* __restrict__ out, int N) {
    const int node = (blockIdx.x * blockDim.x + threadIdx.x) >> 6;
    const int lane = threadIdx.x & 63;
    if (node >= N) return;
    const int beg = rowptr[node], end = rowptr[node + 1];
    const float dd = dinv[node];
    const int g  = lane >> 3;              // 0..7
    const int ci = lane & 7;               // channels [8ci, 8ci+8)
    const uint4* hp = (const uint4*)h;     // 8 uint4 per row

    float acc[8];
    #pragma unroll
    for (int q = 0; q < 8; ++q) acc[q] = 0.f;

    for (int i0 = beg; i0 < end; i0 += 64) {
        const int m = min(64, end - i0);
        int s_l = 0; float nm_l = 0.f;
        if (lane < m) {
            int2 p = epack[i0 + lane];
            s_l = p.x;
            nm_l = __int_as_float(p.y) * dinv[p.x];
        }
        int j = 0;
        for (; j + 32 <= m; j += 32) {                // 4 gathers in flight
            #pragma unroll
            for (int k = 0; k < 4; ++k) {
                int idx = j + 8 * k + g;
                int   s  = __shfl(s_l, idx, 64);
                float nm = __shfl(nm_l, idx, 64);
                gacc(hp, 8, ci, s, nm, acc);
            }
        }
        for (; j < m; j += 8) {                       // tail: <=7 padded edges/round
            int idx = j + g;
            int   s  = __shfl(s_l, idx, 64);
            float nm = __shfl(nm_l, idx, 64);
            gacc(hp, 8, ci, s, nm, acc);
        }
    }
    // combine 8 edge subgroups (lane bits 3,4,5)
    #pragma unroll
    for (int q = 0; q < 8; ++q) {
        acc[q] += __shfl_xor(acc[q], 8, 64);
        acc[q] += __shfl_xor(acc[q], 16, 64);
        acc[q] += __shfl_xor(acc[q], 32, 64);
    }
    // self + bias
    uint4 hv = hp[(size_t)node * 8 + ci];
    float hn[8];
    unpack2(hv.x, hn[0], hn[1]); unpack2(hv.y, hn[2], hn[3]);
    unpack2(hv.z, hn[4], hn[5]); unpack2(hv.w, hn[6], hn[7]);
    float4 b0 = *reinterpret_cast<const float4*>(b + 8 * ci);
    float4 b1v = *reinterpret_cast<const float4*>(b + 8 * ci + 4);
    const float bb[8] = {b0.x, b0.y, b0.z, b0.w, b1v.x, b1v.y, b1v.z, b1v.w};
    float res[8];
    #pragma unroll
    for (int q = 0; q < 8; ++q)
        res[q] = fmaf(acc[q], dd, fmaf(hn[q], dd * dd, bb[q]));

    // log_softmax over 64 channels: local 8 -> cross-ci (lane bits 0,1,2)
    float mx = res[0];
    #pragma unroll
    for (int q = 1; q < 8; ++q) mx = fmaxf(mx, res[q]);
    mx = fmaxf(mx, __shfl_xor(mx, 1, 64));
    mx = fmaxf(mx, __shfl_xor(mx, 2, 64));
    mx = fmaxf(mx, __shfl_xor(mx, 4, 64));
    float sm = 0.f;
    #pragma unroll
    for (int q = 0; q < 8; ++q) sm += expf(res[q] - mx);
    sm += __shfl_xor(sm, 1, 64);
    sm += __shfl_xor(sm, 2, 64);
    sm += __shfl_xor(sm, 4, 64);
    float lse = mx + logf(sm);
    if (g == 0) {
        float4 o0 = make_float4(res[0] - lse, res[1] - lse, res[2] - lse, res[3] - lse);
        float4 o1 = make_float4(res[4] - lse, res[5] - lse, res[6] - lse, res[7] - lse);
        *reinterpret_cast<float4*>(out + (size_t)node * 64 + 8 * ci)     = o0;
        *reinterpret_cast<float4*>(out + (size_t)node * 64 + 8 * ci + 4) = o1;
    }
}

extern "C" void kernel_launch(void* const* d_in, const int* in_sizes, int n_in,
                              void* d_out, int out_size, void* d_ws, size_t ws_size,
                              hipStream_t stream) {
    const float* x  = (const float*)d_in[0];
    const int*   ei = (const int*)d_in[1];     // [2,E]: src = ei[e], dst = ei[E+e]
    const float* w  = (const float*)d_in[2];
    const float* W1 = (const float*)d_in[3];
    const float* b1 = (const float*)d_in[4];
    const float* W2 = (const float*)d_in[5];
    const float* b2 = (const float*)d_in[6];
    float* out = (float*)d_out;

    const int N = in_sizes[0] / CH_IN;
    const int E = in_sizes[2];
    const int NB = (N + 255) / 256;            // scan blocks (<= 256)

    // workspace carve (float units; epack 8B-aligned, bf16 arrays 16B-aligned)
    float* ws0   = (float*)d_ws;
    float* ws    = ws0;
    float* dinv  = ws;               ws += N;
    int*   rowptr= (int*)ws;         ws += (N + 2);
    int*   bsum  = (int*)ws;         ws += 256;
    int*   cnt_s = (int*)ws;         ws += (size_t)NSH * N;
    int*   eord  = (int*)ws;         ws += E;
    int2*  epack = (int2*)ws;        ws += (size_t)2 * E;
    { size_t off = (size_t)(ws - ws0) & 3; if (off) ws += 4 - off; }
    unsigned short* w1t  = (unsigned short*)ws;  ws += (size_t)CH_HID * 128 / 2;
    unsigned short* w2t  = (unsigned short*)ws;  ws += (size_t)CH_OUT * 128 / 2;
    unsigned short* h1   = (unsigned short*)ws;  ws += (size_t)N * CH_HID / 2;
    unsigned short* out1 = (unsigned short*)ws;  ws += (size_t)N * CH_HID / 2;
    unsigned short* h2   = (unsigned short*)ws;  ws += (size_t)N * CH_OUT / 2;

    const int B = 256;
    const int setup_total = NSH * N + CH_HID * 128 + CH_OUT * 128;

    // 0) fused setup: zero shard counters + both weight transposes
    k_setup<<<(setup_total + B - 1) / B, B, 0, stream>>>(cnt_s, NSH * N, W1, w1t, W2, w2t);

    // 1) fat kernel: GEMM1 co-scheduled with sharded histogram
    {
        const int nbg = (N + 63) / 64;
        const int nbh = (E + B - 1) / B;
        k_fat<<<nbg + nbh, B, 0, stream>>>(x, w1t, h1, N, nbg, ei, cnt_s, eord, E);
    }

    // 2) shard prefix + block scan; cross-block add; atomic-free fill; degree
    k_shardscan_pre<<<NB, 256, 0, stream>>>(cnt_s, rowptr, bsum, N);
    k_scan_add<<<NB, 256, 0, stream>>>(rowptr, bsum, N);
    k_fill<<<(E + B - 1) / B, B, 0, stream>>>(ei, w, eord, rowptr, cnt_s, epack, E, N);
    k_degdinv<<<(N * 64 + B - 1) / B, B, 0, stream>>>(rowptr, epack, dinv, N);

    // 3) out1 = b1 + self + neighbor aggregate (16B/lane gathers, adaptive rounds)
    k_agg128<<<(N * 64 + B - 1) / B, B, 0, stream>>>(rowptr, epack, dinv, h1, b1, out1, N);

    // 4) h2 = relu(out1) @ W2  (bf16 in w/ fused relu, MFMA, bf16 out)
    k_gemm_mfma<CH_OUT, true, unsigned short><<<(N + 63) / 64, 256, 0, stream>>>(out1, w2t, h2, N);

    // 5) out = log_softmax(b2 + self + aggregate), fused, fp32 into d_out
    k_agg64<<<(N * 64 + B - 1) / B, B, 0, stream>>>(rowptr, epack, dinv, h2, b2, out, N);
}

// Round 12
// 144.623 us; speedup vs baseline: 1.2474x; 1.1205x over previous
//
#include <hip/hip_runtime.h>
#include <math.h>

static constexpr int CH_IN  = 128;
static constexpr int CH_HID = 128;
static constexpr int CH_OUT = 64;
static constexpr int NBLK1  = 256;   // edge-pass blocks (count & scatter)

typedef __attribute__((ext_vector_type(8))) short bf16x8;
typedef __attribute__((ext_vector_type(4))) float f32x4;

// ---------- bf16 helpers ----------

__device__ __forceinline__ float bf2f(unsigned short u) {
    return __uint_as_float(((unsigned int)u) << 16);
}
__device__ __forceinline__ unsigned short f2bf(float f) {
    unsigned int u = __float_as_uint(f);
    u = (u + 0x7fffu + ((u >> 16) & 1u)) >> 16;   // RNE
    return (unsigned short)u;
}
__device__ __forceinline__ unsigned int pack2(float lo, float hi) {
    return (unsigned int)f2bf(lo) | ((unsigned int)f2bf(hi) << 16);
}
__device__ __forceinline__ void unpack2(unsigned int u, float& lo, float& hi) {
    lo = __uint_as_float(u << 16);
    hi = __uint_as_float(u & 0xffff0000u);
}
__device__ __forceinline__ unsigned int relu2(unsigned int u) {
    unsigned int m = 0;
    if (!(u & 0x8000u)) m |= 0xffffu;
    if (!(u & 0x80000000u)) m |= 0xffff0000u;
    return u & m;
}

// gather one 16B row-segment (8 bf16 ch) and accumulate into acc[0..7]
__device__ __forceinline__ void gacc(const uint4* __restrict__ hp, int stride, int ci,
                                     int s, float nm, float* acc) {
    uint4 v = hp[(size_t)s * stride + ci];
    float lo, hi;
    unpack2(v.x, lo, hi); acc[0] = fmaf(lo, nm, acc[0]); acc[1] = fmaf(hi, nm, acc[1]);
    unpack2(v.y, lo, hi); acc[2] = fmaf(lo, nm, acc[2]); acc[3] = fmaf(hi, nm, acc[3]);
    unpack2(v.z, lo, hi); acc[4] = fmaf(lo, nm, acc[4]); acc[5] = fmaf(hi, nm, acc[5]);
    unpack2(v.w, lo, hi); acc[6] = fmaf(lo, nm, acc[6]); acc[7] = fmaf(hi, nm, acc[7]);
}

__device__ __forceinline__ int block_incl_scan_256(int v, int lane, int wid) {
    __shared__ int wtot[4];
    int s = v;
    #pragma unroll
    for (int off = 1; off < 64; off <<= 1) {
        int t = __shfl_up(s, off, 64);
        if (lane >= off) s += t;
    }
    if (lane == 63) wtot[wid] = s;
    __syncthreads();
    int woff = 0;
    for (int j = 0; j < wid; ++j) woff += wtot[j];
    return s + woff;
}

// ---------- setup: transpose/convert both weights to bf16 Wt[c][k] ----------

__global__ void k_setup(const float* __restrict__ W1, unsigned short* __restrict__ w1t,
                        const float* __restrict__ W2, unsigned short* __restrict__ w2t) {
    int j = blockIdx.x * blockDim.x + threadIdx.x;
    if (j < CH_HID * 128) {
        int c = j >> 7, k = j & 127;
        w1t[(size_t)c * 128 + k] = f2bf(W1[(size_t)k * CH_HID + c]);
        return;
    }
    j -= CH_HID * 128;
    if (j < CH_OUT * 128) {
        int c = j >> 7, k = j & 127;
        w2t[(size_t)c * 128 + k] = f2bf(W2[(size_t)k * CH_OUT + c]);
    }
}

// ---------- MFMA GEMM body ----------

template<int COLS, bool RELU_IN, typename TIN>
__device__ __forceinline__ void gemm_body(const TIN* __restrict__ X,
                                          const unsigned short* __restrict__ Wt,
                                          unsigned short* __restrict__ H, int N, int blk) {
    constexpr int NCT = COLS / 16;
    __shared__ unsigned short As[64 * 136];
    const int tid = threadIdx.x;
    const int lane = tid & 63, wv = tid >> 6;
    const int row0 = blk * 64;

    if constexpr (sizeof(TIN) == 4) {
        #pragma unroll
        for (int j = 0; j < 8; ++j) {
            int f = j * 256 + tid;
            int row = f >> 5, col = (f & 31) * 4;
            float4 v = make_float4(0.f, 0.f, 0.f, 0.f);
            if (row0 + row < N)
                v = *reinterpret_cast<const float4*>((const float*)X + (size_t)(row0 + row) * CH_IN + col);
            uint2 p;
            p.x = pack2(v.x, v.y);
            p.y = pack2(v.z, v.w);
            *reinterpret_cast<uint2*>(&As[row * 136 + col]) = p;
        }
    } else {
        #pragma unroll
        for (int j = 0; j < 4; ++j) {
            int f = j * 256 + tid;
            int row = f >> 4, col = (f & 15) * 8;
            uint4 v = make_uint4(0u, 0u, 0u, 0u);
            if (row0 + row < N) {
                v = *reinterpret_cast<const uint4*>((const unsigned short*)X + (size_t)(row0 + row) * CH_IN + col);
                if (RELU_IN) {
                    v.x = relu2(v.x); v.y = relu2(v.y);
                    v.z = relu2(v.z); v.w = relu2(v.w);
                }
            }
            *reinterpret_cast<uint4*>(&As[row * 136 + col]) = v;
        }
    }
    __syncthreads();

    const int rw0  = wv * 16;
    const int arow = rw0 + (lane & 15);
    const int kgrp = (lane >> 4) * 8;
    f32x4 acc[NCT];
    #pragma unroll
    for (int c = 0; c < NCT; ++c) acc[c] = f32x4{0.f, 0.f, 0.f, 0.f};

    #pragma unroll
    for (int kk = 0; kk < 4; ++kk) {
        bf16x8 af = *reinterpret_cast<const bf16x8*>(&As[arow * 136 + kk * 32 + kgrp]);
        #pragma unroll
        for (int ct = 0; ct < NCT; ++ct) {
            bf16x8 bf = *reinterpret_cast<const bf16x8*>(
                Wt + (size_t)(ct * 16 + (lane & 15)) * 128 + kk * 32 + kgrp);
            acc[ct] = __builtin_amdgcn_mfma_f32_16x16x32_bf16(af, bf, acc[ct], 0, 0, 0);
        }
    }

    const int orow0 = row0 + rw0 + (lane >> 4) * 4;
    const int ocol  = lane & 15;
    #pragma unroll
    for (int ct = 0; ct < NCT; ++ct) {
        #pragma unroll
        for (int r = 0; r < 4; ++r) {
            int row = orow0 + r;
            if (row < N) H[(size_t)row * COLS + ct * 16 + ocol] = f2bf(acc[ct][r]);
        }
    }
}

// ---------- fat kernel: GEMM1 ∥ bucket-count pass (atomic-free CSR, stage 1) ----------
// bucket = dst >> 8; per-(bucket,block) counts via LDS histogram, plain stores out.

__global__ void __launch_bounds__(256) k_fat(
        const float* __restrict__ x, const unsigned short* __restrict__ w1t,
        unsigned short* __restrict__ h1, int N, int nbg,
        const int* __restrict__ ei, int* __restrict__ cnt_bk, int E, int nbk, int epb) {
    __shared__ int bcnt[256];
    if ((int)blockIdx.x < nbg) {
        gemm_body<CH_HID, false, float>(x, w1t, h1, N, blockIdx.x);
    } else {
        const int b = blockIdx.x - nbg;
        const int tid = threadIdx.x;
        bcnt[tid] = 0;
        __syncthreads();
        const int e0 = b * epb, e1 = min(E, e0 + epb);
        for (int e = e0 + tid; e < e1; e += 256)
            atomicAdd(&bcnt[ei[E + e] >> 8], 1);          // LDS atomic
        __syncthreads();
        if (tid < nbk) cnt_bk[tid * NBLK1 + b] = bcnt[tid];
    }
}

// standalone GEMM (layer 2)
template<int COLS, bool RELU_IN, typename TIN>
__global__ void __launch_bounds__(256) k_gemm_mfma(const TIN* __restrict__ X,
        const unsigned short* __restrict__ Wt, unsigned short* __restrict__ H, int N) {
    gemm_body<COLS, RELU_IN, TIN>(X, Wt, H, N, blockIdx.x);
}

// ---------- stage 2a: per-bucket cross-block scan (grid = nbk blocks) ----------

__global__ void k_bscan(const int* __restrict__ cnt_bk, int* __restrict__ off_bk,
                        int* __restrict__ btot) {
    const int k = blockIdx.x, tid = threadIdx.x, lane = tid & 63, wid = tid >> 6;
    int c = cnt_bk[k * NBLK1 + tid];
    int incl = block_incl_scan_256(c, lane, wid);
    off_bk[k * NBLK1 + tid] = incl - c;                   // exclusive over blocks
    if (tid == 255) btot[k] = incl;
}

// ---------- stage 2b: bucket bases (1 block) ----------

__global__ void k_bbase(const int* __restrict__ btot, int* __restrict__ gbase,
                        int* __restrict__ rowptr, int nbk, int E) {
    const int tid = threadIdx.x, lane = tid & 63, wid = tid >> 6;
    int v = (tid < nbk) ? btot[tid] : 0;
    int incl = block_incl_scan_256(v, lane, wid);
    if (tid < nbk) gbase[tid] = incl - v;                 // exclusive
    if (tid == 0) { gbase[nbk] = E; rowptr[0] = 0; }
}

// ---------- stage 3: scatter edges into bucket-grouped ebuck (LDS cursors) ----------

__global__ void k_scat(const int* __restrict__ ei, const float* __restrict__ w,
                       const int* __restrict__ gbase, const int* __restrict__ off_bk,
                       uint2* __restrict__ ebuck, int E, int nbk, int epb) {
    __shared__ int lcur[256];
    const int b = blockIdx.x, tid = threadIdx.x;
    if (tid < nbk) lcur[tid] = gbase[tid] + off_bk[tid * NBLK1 + b];
    __syncthreads();
    const int e0 = b * epb, e1 = min(E, e0 + epb);
    for (int e = e0 + tid; e < e1; e += 256) {
        unsigned int s = (unsigned int)ei[e];
        unsigned int d = (unsigned int)ei[E + e];
        int pos = atomicAdd(&lcur[d >> 8], 1);            // LDS atomic
        ebuck[pos] = make_uint2((d << 16) | s, __float_as_uint(w[e]));
    }
}

// ---------- stage 4: per-bucket CSR + fused weighted-degree/dinv ----------
// Block k: nodes [256k, 256k+256), edges [gbase[k], gbase[k+1]).

__global__ void k_csr(const uint2* __restrict__ ebuck, const int* __restrict__ gbase,
                      int* __restrict__ rowptr, float* __restrict__ dinv,
                      int2* __restrict__ epack, int N) {
    __shared__ int ncnt[256];
    __shared__ float wsm[256];
    const int k = blockIdx.x, tid = threadIdx.x, lane = tid & 63, wid = tid >> 6;
    const int ebeg = gbase[k], eend = gbase[k + 1];
    ncnt[tid] = 0; wsm[tid] = 0.f;
    __syncthreads();
    for (int i = ebeg + tid; i < eend; i += 256) {
        uint2 p = ebuck[i];
        int dl = (p.x >> 16) & 255;
        atomicAdd(&ncnt[dl], 1);
        atomicAdd(&wsm[dl], __uint_as_float(p.y));        // LDS float atomic
    }
    __syncthreads();
    int c = ncnt[tid];
    int incl = block_incl_scan_256(c, lane, wid);
    const int nd = k * 256 + tid;
    if (nd < N) {
        rowptr[nd + 1] = ebeg + incl;
        dinv[nd] = rsqrtf(1.0f + wsm[tid]);
    }
    __syncthreads();
    ncnt[tid] = ebeg + incl - c;                          // node cursor (global pos)
    __syncthreads();
    for (int i = ebeg + tid; i < eend; i += 256) {
        uint2 p = ebuck[i];
        int dl = (p.x >> 16) & 255;
        int pos = atomicAdd(&ncnt[dl], 1);
        epack[pos] = make_int2((int)(p.x & 0xFFFFu), (int)p.y);
    }
}

// ---------- CSR aggregation, 16B/lane gathers, degree-adaptive rounds ----------

__global__ void k_agg128(const int* __restrict__ rowptr, const int2* __restrict__ epack,
                         const float* __restrict__ dinv, const unsigned short* __restrict__ h,
                         const float* __restrict__ b, unsigned short* __restrict__ out, int N) {
    const int node = (blockIdx.x * blockDim.x + threadIdx.x) >> 6;
    const int lane = threadIdx.x & 63;
    if (node >= N) return;
    const int beg = rowptr[node], end = rowptr[node + 1];
    const float dd = dinv[node];
    const int g  = lane >> 4;              // 0..3
    const int ci = lane & 15;              // channels [8ci, 8ci+8)
    const uint4* hp = (const uint4*)h;     // 16 uint4 per row

    float acc[8];
    #pragma unroll
    for (int q = 0; q < 8; ++q) acc[q] = 0.f;

    for (int i0 = beg; i0 < end; i0 += 64) {
        const int m = min(64, end - i0);
        int s_l = 0; float nm_l = 0.f;
        if (lane < m) {
            int2 p = epack[i0 + lane];
            s_l = p.x;
            nm_l = __int_as_float(p.y) * dinv[p.x];
        }
        int j = 0;
        for (; j + 16 <= m; j += 16) {
            #pragma unroll
            for (int kk = 0; kk < 4; ++kk) {
                int idx = j + 4 * kk + g;
                int   s  = __shfl(s_l, idx, 64);
                float nm = __shfl(nm_l, idx, 64);
                gacc(hp, 16, ci, s, nm, acc);
            }
        }
        for (; j < m; j += 4) {
            int idx = j + g;
            int   s  = __shfl(s_l, idx, 64);
            float nm = __shfl(nm_l, idx, 64);
            gacc(hp, 16, ci, s, nm, acc);
        }
    }
    #pragma unroll
    for (int q = 0; q < 8; ++q) {
        acc[q] += __shfl_xor(acc[q], 16, 64);
        acc[q] += __shfl_xor(acc[q], 32, 64);
    }
    uint4 hv = hp[(size_t)node * 16 + ci];
    float hn[8];
    unpack2(hv.x, hn[0], hn[1]); unpack2(hv.y, hn[2], hn[3]);
    unpack2(hv.z, hn[4], hn[5]); unpack2(hv.w, hn[6], hn[7]);
    float4 b0 = *reinterpret_cast<const float4*>(b + 8 * ci);
    float4 b1v = *reinterpret_cast<const float4*>(b + 8 * ci + 4);
    const float bb[8] = {b0.x, b0.y, b0.z, b0.w, b1v.x, b1v.y, b1v.z, b1v.w};
    float res[8];
    #pragma unroll
    for (int q = 0; q < 8; ++q)
        res[q] = fmaf(acc[q], dd, fmaf(hn[q], dd * dd, bb[q]));
    if (g == 0) {
        uint4 o;
        o.x = pack2(res[0], res[1]); o.y = pack2(res[2], res[3]);
        o.z = pack2(res[4], res[5]); o.w = pack2(res[6], res[7]);
        ((uint4*)out)[(size_t)node * 16 + ci] = o;
    }
}

__global__ void k_agg64(const int* __restrict__ rowptr, const int2* __restrict__ epack,
                        const float* __restrict__ dinv, const unsigned short* __restrict__ h,
                        const float* __restrict__ b, float* __restrict__ out, int N) {
    const int node = (blockIdx.x * blockDim.x + threadIdx.x) >> 6;
    const int lane = threadIdx.x & 63;
    if (node >= N) return;
    const int beg = rowptr[node], end = rowptr[node + 1];
    const float dd = dinv[node];
    const int g  = lane >> 3;              // 0..7
    const int ci = lane & 7;               // channels [8ci, 8ci+8)
    const uint4* hp = (const uint4*)h;     // 8 uint4 per row

    float acc[8];
    #pragma unroll
    for (int q = 0; q < 8; ++q) acc[q] = 0.f;

    for (int i0 = beg; i0 < end; i0 += 64) {
        const int m = min(64, end - i0);
        int s_l = 0; float nm_l = 0.f;
        if (lane < m) {
            int2 p = epack[i0 + lane];
            s_l = p.x;
            nm_l = __int_as_float(p.y) * dinv[p.x];
        }
        int j = 0;
        for (; j + 32 <= m; j += 32) {
            #pragma unroll
            for (int kk = 0; kk < 4; ++kk) {
                int idx = j + 8 * kk + g;
                int   s  = __shfl(s_l, idx, 64);
                float nm = __shfl(nm_l, idx, 64);
                gacc(hp, 8, ci, s, nm, acc);
            }
        }
        for (; j < m; j += 8) {
            int idx = j + g;
            int   s  = __shfl(s_l, idx, 64);
            float nm = __shfl(nm_l, idx, 64);
            gacc(hp, 8, ci, s, nm, acc);
        }
    }
    #pragma unroll
    for (int q = 0; q < 8; ++q) {
        acc[q] += __shfl_xor(acc[q], 8, 64);
        acc[q] += __shfl_xor(acc[q], 16, 64);
        acc[q] += __shfl_xor(acc[q], 32, 64);
    }
    uint4 hv = hp[(size_t)node * 8 + ci];
    float hn[8];
    unpack2(hv.x, hn[0], hn[1]); unpack2(hv.y, hn[2], hn[3]);
    unpack2(hv.z, hn[4], hn[5]); unpack2(hv.w, hn[6], hn[7]);
    float4 b0 = *reinterpret_cast<const float4*>(b + 8 * ci);
    float4 b1v = *reinterpret_cast<const float4*>(b + 8 * ci + 4);
    const float bb[8] = {b0.x, b0.y, b0.z, b0.w, b1v.x, b1v.y, b1v.z, b1v.w};
    float res[8];
    #pragma unroll
    for (int q = 0; q < 8; ++q)
        res[q] = fmaf(acc[q], dd, fmaf(hn[q], dd * dd, bb[q]));

    float mx = res[0];
    #pragma unroll
    for (int q = 1; q < 8; ++q) mx = fmaxf(mx, res[q]);
    mx = fmaxf(mx, __shfl_xor(mx, 1, 64));
    mx = fmaxf(mx, __shfl_xor(mx, 2, 64));
    mx = fmaxf(mx, __shfl_xor(mx, 4, 64));
    float sm = 0.f;
    #pragma unroll
    for (int q = 0; q < 8; ++q) sm += expf(res[q] - mx);
    sm += __shfl_xor(sm, 1, 64);
    sm += __shfl_xor(sm, 2, 64);
    sm += __shfl_xor(sm, 4, 64);
    float lse = mx + logf(sm);
    if (g == 0) {
        float4 o0 = make_float4(res[0] - lse, res[1] - lse, res[2] - lse, res[3] - lse);
        float4 o1 = make_float4(res[4] - lse, res[5] - lse, res[6] - lse, res[7] - lse);
        *reinterpret_cast<float4*>(out + (size_t)node * 64 + 8 * ci)     = o0;
        *reinterpret_cast<float4*>(out + (size_t)node * 64 + 8 * ci + 4) = o1;
    }
}

extern "C" void kernel_launch(void* const* d_in, const int* in_sizes, int n_in,
                              void* d_out, int out_size, void* d_ws, size_t ws_size,
                              hipStream_t stream) {
    const float* x  = (const float*)d_in[0];
    const int*   ei = (const int*)d_in[1];     // [2,E]: src = ei[e], dst = ei[E+e]
    const float* w  = (const float*)d_in[2];
    const float* W1 = (const float*)d_in[3];
    const float* b1 = (const float*)d_in[4];
    const float* W2 = (const float*)d_in[5];
    const float* b2 = (const float*)d_in[6];
    float* out = (float*)d_out;

    const int N = in_sizes[0] / CH_IN;         // 50000 (< 65536: 16-bit packing valid)
    const int E = in_sizes[2];
    const int NBK = (N + 255) >> 8;            // buckets of 256 nodes (196)
    const int EPB = (E + NBLK1 - 1) / NBLK1;   // edges per count/scatter block

    // workspace carve (float units; uint2/int2 8B-aligned, bf16 arrays 16B-aligned)
    float* ws0   = (float*)d_ws;
    float* ws    = ws0;
    float* dinv  = ws;               ws += N;
    int*   rowptr= (int*)ws;         ws += (N + 2);
    int*   cnt_bk= (int*)ws;         ws += 256 * NBLK1;
    int*   off_bk= (int*)ws;         ws += 256 * NBLK1;
    int*   btot  = (int*)ws;         ws += 256;
    int*   gbase = (int*)ws;         ws += 260;
    uint2* ebuck = (uint2*)ws;       ws += (size_t)2 * E;
    int2*  epack = (int2*)ws;        ws += (size_t)2 * E;
    { size_t off = (size_t)(ws - ws0) & 3; if (off) ws += 4 - off; }   // 16B align
    unsigned short* w1t  = (unsigned short*)ws;  ws += (size_t)CH_HID * 128 / 2;
    unsigned short* w2t  = (unsigned short*)ws;  ws += (size_t)CH_OUT * 128 / 2;
    unsigned short* h1   = (unsigned short*)ws;  ws += (size_t)N * CH_HID / 2;
    unsigned short* out1 = (unsigned short*)ws;  ws += (size_t)N * CH_HID / 2;
    unsigned short* h2   = (unsigned short*)ws;  ws += (size_t)N * CH_OUT / 2;

    const int B = 256;

    // 0) weight transposes (tiny)
    k_setup<<<(CH_HID * 128 + CH_OUT * 128 + B - 1) / B, B, 0, stream>>>(W1, w1t, W2, w2t);

    // 1) GEMM1 co-scheduled with atomic-free bucket count
    {
        const int nbg = (N + 63) / 64;
        k_fat<<<nbg + NBLK1, B, 0, stream>>>(x, w1t, h1, N, nbg, ei, cnt_bk, E, NBK, EPB);
    }

    // 2) scans: per-bucket cross-block + bucket bases
    k_bscan<<<NBK, 256, 0, stream>>>(cnt_bk, off_bk, btot);
    k_bbase<<<1, 256, 0, stream>>>(btot, gbase, rowptr, NBK, E);

    // 3) scatter into bucket order (LDS cursors, no global atomics)
    k_scat<<<NBLK1, 256, 0, stream>>>(ei, w, gbase, off_bk, ebuck, E, NBK, EPB);

    // 4) per-bucket CSR + dinv + final epack
    k_csr<<<NBK, 256, 0, stream>>>(ebuck, gbase, rowptr, dinv, epack, N);

    // 5) out1 = b1 + self + neighbor aggregate
    k_agg128<<<(N * 64 + B - 1) / B, B, 0, stream>>>(rowptr, epack, dinv, h1, b1, out1, N);

    // 6) h2 = relu(out1) @ W2
    k_gemm_mfma<CH_OUT, true, unsigned short><<<(N + 63) / 64, 256, 0, stream>>>(out1, w2t, h2, N);

    // 7) out = log_softmax(b2 + self + aggregate), fused, fp32 into d_out
    k_agg64<<<(N * 64 + B - 1) / B, B, 0, stream>>>(rowptr, epack, dinv, h2, b2, out, N);
}

// Round 13
// 127.082 us; speedup vs baseline: 1.4196x; 1.1380x over previous
//
#include <hip/hip_runtime.h>
#include <math.h>

static constexpr int CH_IN  = 128;
static constexpr int CH_HID = 128;
static constexpr int CH_OUT = 64;
static constexpr int NBLK1  = 256;   // edge-pass blocks (count & scatter)

typedef __attribute__((ext_vector_type(8))) short bf16x8;
typedef __attribute__((ext_vector_type(4))) float f32x4;

// ---------- bf16 helpers ----------

__device__ __forceinline__ float bf2f(unsigned short u) {
    return __uint_as_float(((unsigned int)u) << 16);
}
__device__ __forceinline__ unsigned short f2bf(float f) {
    unsigned int u = __float_as_uint(f);
    u = (u + 0x7fffu + ((u >> 16) & 1u)) >> 16;   // RNE
    return (unsigned short)u;
}
__device__ __forceinline__ unsigned int pack2(float lo, float hi) {
    return (unsigned int)f2bf(lo) | ((unsigned int)f2bf(hi) << 16);
}
__device__ __forceinline__ void unpack2(unsigned int u, float& lo, float& hi) {
    lo = __uint_as_float(u << 16);
    hi = __uint_as_float(u & 0xffff0000u);
}
__device__ __forceinline__ unsigned int relu2(unsigned int u) {
    unsigned int m = 0;
    if (!(u & 0x8000u)) m |= 0xffffu;
    if (!(u & 0x80000000u)) m |= 0xffff0000u;
    return u & m;
}

// gather one 16B row-segment (8 bf16 ch) and accumulate into acc[0..7]
__device__ __forceinline__ void gacc(const uint4* __restrict__ hp, int stride, int ci,
                                     int s, float nm, float* acc) {
    uint4 v = hp[(size_t)s * stride + ci];
    float lo, hi;
    unpack2(v.x, lo, hi); acc[0] = fmaf(lo, nm, acc[0]); acc[1] = fmaf(hi, nm, acc[1]);
    unpack2(v.y, lo, hi); acc[2] = fmaf(lo, nm, acc[2]); acc[3] = fmaf(hi, nm, acc[3]);
    unpack2(v.z, lo, hi); acc[4] = fmaf(lo, nm, acc[4]); acc[5] = fmaf(hi, nm, acc[5]);
    unpack2(v.w, lo, hi); acc[6] = fmaf(lo, nm, acc[6]); acc[7] = fmaf(hi, nm, acc[7]);
}

__device__ __forceinline__ int block_incl_scan_256(int v, int lane, int wid) {
    __shared__ int wtot[4];
    int s = v;
    #pragma unroll
    for (int off = 1; off < 64; off <<= 1) {
        int t = __shfl_up(s, off, 64);
        if (lane >= off) s += t;
    }
    if (lane == 63) wtot[wid] = s;
    __syncthreads();
    int woff = 0;
    for (int j = 0; j < wid; ++j) woff += wtot[j];
    return s + woff;
}

// ---------- MFMA GEMM body with in-LDS W transpose (fp32 W -> bf16 Wt[c][136]) ----------

template<int COLS, bool RELU_IN, typename TIN>
__device__ __forceinline__ void gemm_body(const TIN* __restrict__ X,
                                          const float* __restrict__ W,
                                          unsigned short* __restrict__ H, int N, int blk) {
    constexpr int NCT = COLS / 16;
    __shared__ unsigned short As[64 * 136];
    __shared__ unsigned short Wt[COLS * 136];
    const int tid = threadIdx.x;
    const int lane = tid & 63, wv = tid >> 6;
    const int row0 = blk * 64;

    // stage W transposed: f = k*COLS + c (coalesced fp32 read), Wt[c][k]
    #pragma unroll
    for (int it = 0; it < (128 * COLS) / 256; ++it) {
        int f = it * 256 + tid;
        int k = f / COLS, c = f & (COLS - 1);
        Wt[c * 136 + k] = f2bf(W[f]);
    }

    if constexpr (sizeof(TIN) == 4) {
        #pragma unroll
        for (int j = 0; j < 8; ++j) {
            int f = j * 256 + tid;
            int row = f >> 5, col = (f & 31) * 4;
            float4 v = make_float4(0.f, 0.f, 0.f, 0.f);
            if (row0 + row < N)
                v = *reinterpret_cast<const float4*>((const float*)X + (size_t)(row0 + row) * CH_IN + col);
            uint2 p;
            p.x = pack2(v.x, v.y);
            p.y = pack2(v.z, v.w);
            *reinterpret_cast<uint2*>(&As[row * 136 + col]) = p;
        }
    } else {
        #pragma unroll
        for (int j = 0; j < 4; ++j) {
            int f = j * 256 + tid;
            int row = f >> 4, col = (f & 15) * 8;
            uint4 v = make_uint4(0u, 0u, 0u, 0u);
            if (row0 + row < N) {
                v = *reinterpret_cast<const uint4*>((const unsigned short*)X + (size_t)(row0 + row) * CH_IN + col);
                if (RELU_IN) {
                    v.x = relu2(v.x); v.y = relu2(v.y);
                    v.z = relu2(v.z); v.w = relu2(v.w);
                }
            }
            *reinterpret_cast<uint4*>(&As[row * 136 + col]) = v;
        }
    }
    __syncthreads();

    const int rw0  = wv * 16;
    const int arow = rw0 + (lane & 15);
    const int kgrp = (lane >> 4) * 8;
    f32x4 acc[NCT];
    #pragma unroll
    for (int c = 0; c < NCT; ++c) acc[c] = f32x4{0.f, 0.f, 0.f, 0.f};

    #pragma unroll
    for (int kk = 0; kk < 4; ++kk) {
        bf16x8 af = *reinterpret_cast<const bf16x8*>(&As[arow * 136 + kk * 32 + kgrp]);
        #pragma unroll
        for (int ct = 0; ct < NCT; ++ct) {
            bf16x8 bf = *reinterpret_cast<const bf16x8*>(
                &Wt[(ct * 16 + (lane & 15)) * 136 + kk * 32 + kgrp]);
            acc[ct] = __builtin_amdgcn_mfma_f32_16x16x32_bf16(af, bf, acc[ct], 0, 0, 0);
        }
    }

    const int orow0 = row0 + rw0 + (lane >> 4) * 4;
    const int ocol  = lane & 15;
    #pragma unroll
    for (int ct = 0; ct < NCT; ++ct) {
        #pragma unroll
        for (int r = 0; r < 4; ++r) {
            int row = orow0 + r;
            if (row < N) H[(size_t)row * COLS + ct * 16 + ocol] = f2bf(acc[ct][r]);
        }
    }
}

// ---------- stage 1: bucket count (LDS histogram, no global atomics) ----------

__global__ void k_count(const int* __restrict__ ei, int* __restrict__ cnt_bk,
                        int E, int nbk, int epb) {
    __shared__ int bcnt[256];
    const int b = blockIdx.x, tid = threadIdx.x;
    bcnt[tid] = 0;
    __syncthreads();
    const int e0 = b * epb, e1 = min(E, e0 + epb);
    for (int e = e0 + tid; e < e1; e += 256)
        atomicAdd(&bcnt[ei[E + e] >> 8], 1);              // LDS atomic
    __syncthreads();
    if (tid < nbk) cnt_bk[tid * NBLK1 + b] = bcnt[tid];
}

// ---------- stage 2: per-bucket cross-block scan (grid = nbk blocks) ----------

__global__ void k_bscan(const int* __restrict__ cnt_bk, int* __restrict__ off_bk,
                        int* __restrict__ btot) {
    const int k = blockIdx.x, tid = threadIdx.x, lane = tid & 63, wid = tid >> 6;
    int c = cnt_bk[k * NBLK1 + tid];
    int incl = block_incl_scan_256(c, lane, wid);
    off_bk[k * NBLK1 + tid] = incl - c;                   // exclusive over blocks
    if (tid == 255) btot[k] = incl;
}

// ---------- stage 3 (fat): GEMM1 ∥ scatter into bucket order ----------
// scat blocks recompute bucket bases in-block from btot (196-value scan).

__global__ void __launch_bounds__(256) k_fat(
        const float* __restrict__ x, const float* __restrict__ W1,
        unsigned short* __restrict__ h1, int N, int nbg,
        const int* __restrict__ ei, const float* __restrict__ w,
        const int* __restrict__ btot, const int* __restrict__ off_bk,
        uint2* __restrict__ ebuck, int E, int nbk, int epb) {
    if ((int)blockIdx.x < nbg) {
        gemm_body<CH_HID, false, float>(x, W1, h1, N, blockIdx.x);
    } else {
        __shared__ int lcur[256];
        const int b = blockIdx.x - nbg;
        const int tid = threadIdx.x, lane = tid & 63, wid = tid >> 6;
        int v = (tid < nbk) ? btot[tid] : 0;
        int incl = block_incl_scan_256(v, lane, wid);
        if (tid < nbk) lcur[tid] = (incl - v) + off_bk[tid * NBLK1 + b];
        __syncthreads();
        const int e0 = b * epb, e1 = min(E, e0 + epb);
        for (int e = e0 + tid; e < e1; e += 256) {
            unsigned int s = (unsigned int)ei[e];
            unsigned int d = (unsigned int)ei[E + e];
            int pos = atomicAdd(&lcur[d >> 8], 1);        // LDS atomic
            ebuck[pos] = make_uint2((d << 16) | s, __float_as_uint(w[e]));
        }
    }
}

// standalone GEMM (layer 2), in-LDS W transpose
template<int COLS, bool RELU_IN, typename TIN>
__global__ void __launch_bounds__(256) k_gemm_mfma(const TIN* __restrict__ X,
        const float* __restrict__ W, unsigned short* __restrict__ H, int N) {
    gemm_body<COLS, RELU_IN, TIN>(X, W, H, N, blockIdx.x);
}

// ---------- stage 4: per-bucket CSR + fused weighted-degree/dinv ----------
// Block k: nodes [256k, 256k+256), edges [gbase[k], gbase[k+1]); gbase from btot scan.

__global__ void k_csr(const uint2* __restrict__ ebuck, const int* __restrict__ btot,
                      int* __restrict__ rowptr, float* __restrict__ dinv,
                      int2* __restrict__ epack, int N, int nbk) {
    __shared__ int ncnt[256];
    __shared__ float wsm[256];
    __shared__ int ebeg_s, eend_s;
    const int k = blockIdx.x, tid = threadIdx.x, lane = tid & 63, wid = tid >> 6;
    int v = (tid < nbk) ? btot[tid] : 0;
    int incl0 = block_incl_scan_256(v, lane, wid);
    if (tid == k) { ebeg_s = incl0 - v; eend_s = incl0; }
    ncnt[tid] = 0; wsm[tid] = 0.f;
    __syncthreads();
    const int ebeg = ebeg_s, eend = eend_s;
    for (int i = ebeg + tid; i < eend; i += 256) {
        uint2 p = ebuck[i];
        int dl = (p.x >> 16) & 255;
        atomicAdd(&ncnt[dl], 1);
        atomicAdd(&wsm[dl], __uint_as_float(p.y));        // LDS float atomic
    }
    __syncthreads();
    int c = ncnt[tid];
    int incl = block_incl_scan_256(c, lane, wid);
    const int nd = k * 256 + tid;
    if (nd < N) {
        rowptr[nd + 1] = ebeg + incl;
        dinv[nd] = rsqrtf(1.0f + wsm[tid]);
    }
    if (k == 0 && tid == 0) rowptr[0] = 0;
    __syncthreads();
    ncnt[tid] = ebeg + incl - c;                          // node cursor (global pos)
    __syncthreads();
    for (int i = ebeg + tid; i < eend; i += 256) {
        uint2 p = ebuck[i];
        int dl = (p.x >> 16) & 255;
        int pos = atomicAdd(&ncnt[dl], 1);
        epack[pos] = make_int2((int)(p.x & 0xFFFFu), (int)p.y);
    }
}

// ---------- CSR aggregation, 16B/lane gathers, degree-adaptive rounds ----------

__global__ void k_agg128(const int* __restrict__ rowptr, const int2* __restrict__ epack,
                         const float* __restrict__ dinv, const unsigned short* __restrict__ h,
                         const float* __restrict__ b, unsigned short* __restrict__ out, int N) {
    const int node = (blockIdx.x * blockDim.x + threadIdx.x) >> 6;
    const int lane = threadIdx.x & 63;
    if (node >= N) return;
    const int beg = rowptr[node], end = rowptr[node + 1];
    const float dd = dinv[node];
    const int g  = lane >> 4;              // 0..3
    const int ci = lane & 15;              // channels [8ci, 8ci+8)
    const uint4* hp = (const uint4*)h;     // 16 uint4 per row

    float acc[8];
    #pragma unroll
    for (int q = 0; q < 8; ++q) acc[q] = 0.f;

    for (int i0 = beg; i0 < end; i0 += 64) {
        const int m = min(64, end - i0);
        int s_l = 0; float nm_l = 0.f;
        if (lane < m) {
            int2 p = epack[i0 + lane];
            s_l = p.x;
            nm_l = __int_as_float(p.y) * dinv[p.x];
        }
        int j = 0;
        for (; j + 16 <= m; j += 16) {
            #pragma unroll
            for (int kk = 0; kk < 4; ++kk) {
                int idx = j + 4 * kk + g;
                int   s  = __shfl(s_l, idx, 64);
                float nm = __shfl(nm_l, idx, 64);
                gacc(hp, 16, ci, s, nm, acc);
            }
        }
        for (; j < m; j += 4) {
            int idx = j + g;
            int   s  = __shfl(s_l, idx, 64);
            float nm = __shfl(nm_l, idx, 64);
            gacc(hp, 16, ci, s, nm, acc);
        }
    }
    #pragma unroll
    for (int q = 0; q < 8; ++q) {
        acc[q] += __shfl_xor(acc[q], 16, 64);
        acc[q] += __shfl_xor(acc[q], 32, 64);
    }
    uint4 hv = hp[(size_t)node * 16 + ci];
    float hn[8];
    unpack2(hv.x, hn[0], hn[1]); unpack2(hv.y, hn[2], hn[3]);
    unpack2(hv.z, hn[4], hn[5]); unpack2(hv.w, hn[6], hn[7]);
    float4 b0 = *reinterpret_cast<const float4*>(b + 8 * ci);
    float4 b1v = *reinterpret_cast<const float4*>(b + 8 * ci + 4);
    const float bb[8] = {b0.x, b0.y, b0.z, b0.w, b1v.x, b1v.y, b1v.z, b1v.w};
    float res[8];
    #pragma unroll
    for (int q = 0; q < 8; ++q)
        res[q] = fmaf(acc[q], dd, fmaf(hn[q], dd * dd, bb[q]));
    if (g == 0) {
        uint4 o;
        o.x = pack2(res[0], res[1]); o.y = pack2(res[2], res[3]);
        o.z = pack2(res[4], res[5]); o.w = pack2(res[6], res[7]);
        ((uint4*)out)[(size_t)node * 16 + ci] = o;
    }
}

__global__ void k_agg64(const int* __restrict__ rowptr, const int2* __restrict__ epack,
                        const float* __restrict__ dinv, const unsigned short* __restrict__ h,
                        const float* __restrict__ b, float* __restrict__ out, int N) {
    const int node = (blockIdx.x * blockDim.x + threadIdx.x) >> 6;
    const int lane = threadIdx.x & 63;
    if (node >= N) return;
    const int beg = rowptr[node], end = rowptr[node + 1];
    const float dd = dinv[node];
    const int g  = lane >> 3;              // 0..7
    const int ci = lane & 7;               // channels [8ci, 8ci+8)
    const uint4* hp = (const uint4*)h;     // 8 uint4 per row

    float acc[8];
    #pragma unroll
    for (int q = 0; q < 8; ++q) acc[q] = 0.f;

    for (int i0 = beg; i0 < end; i0 += 64) {
        const int m = min(64, end - i0);
        int s_l = 0; float nm_l = 0.f;
        if (lane < m) {
            int2 p = epack[i0 + lane];
            s_l = p.x;
            nm_l = __int_as_float(p.y) * dinv[p.x];
        }
        int j = 0;
        for (; j + 32 <= m; j += 32) {
            #pragma unroll
            for (int kk = 0; kk < 4; ++kk) {
                int idx = j + 8 * kk + g;
                int   s  = __shfl(s_l, idx, 64);
                float nm = __shfl(nm_l, idx, 64);
                gacc(hp, 8, ci, s, nm, acc);
            }
        }
        for (; j < m; j += 8) {
            int idx = j + g;
            int   s  = __shfl(s_l, idx, 64);
            float nm = __shfl(nm_l, idx, 64);
            gacc(hp, 8, ci, s, nm, acc);
        }
    }
    #pragma unroll
    for (int q = 0; q < 8; ++q) {
        acc[q] += __shfl_xor(acc[q], 8, 64);
        acc[q] += __shfl_xor(acc[q], 16, 64);
        acc[q] += __shfl_xor(acc[q], 32, 64);
    }
    uint4 hv = hp[(size_t)node * 8 + ci];
    float hn[8];
    unpack2(hv.x, hn[0], hn[1]); unpack2(hv.y, hn[2], hn[3]);
    unpack2(hv.z, hn[4], hn[5]); unpack2(hv.w, hn[6], hn[7]);
    float4 b0 = *reinterpret_cast<const float4*>(b + 8 * ci);
    float4 b1v = *reinterpret_cast<const float4*>(b + 8 * ci + 4);
    const float bb[8] = {b0.x, b0.y, b0.z, b0.w, b1v.x, b1v.y, b1v.z, b1v.w};
    float res[8];
    #pragma unroll
    for (int q = 0; q < 8; ++q)
        res[q] = fmaf(acc[q], dd, fmaf(hn[q], dd * dd, bb[q]));

    float mx = res[0];
    #pragma unroll
    for (int q = 1; q < 8; ++q) mx = fmaxf(mx, res[q]);
    mx = fmaxf(mx, __shfl_xor(mx, 1, 64));
    mx = fmaxf(mx, __shfl_xor(mx, 2, 64));
    mx = fmaxf(mx, __shfl_xor(mx, 4, 64));
    float sm = 0.f;
    #pragma unroll
    for (int q = 0; q < 8; ++q) sm += expf(res[q] - mx);
    sm += __shfl_xor(sm, 1, 64);
    sm += __shfl_xor(sm, 2, 64);
    sm += __shfl_xor(sm, 4, 64);
    float lse = mx + logf(sm);
    if (g == 0) {
        float4 o0 = make_float4(res[0] - lse, res[1] - lse, res[2] - lse, res[3] - lse);
        float4 o1 = make_float4(res[4] - lse, res[5] - lse, res[6] - lse, res[7] - lse);
        *reinterpret_cast<float4*>(out + (size_t)node * 64 + 8 * ci)     = o0;
        *reinterpret_cast<float4*>(out + (size_t)node * 64 + 8 * ci + 4) = o1;
    }
}

extern "C" void kernel_launch(void* const* d_in, const int* in_sizes, int n_in,
                              void* d_out, int out_size, void* d_ws, size_t ws_size,
                              hipStream_t stream) {
    const float* x  = (const float*)d_in[0];
    const int*   ei = (const int*)d_in[1];     // [2,E]: src = ei[e], dst = ei[E+e]
    const float* w  = (const float*)d_in[2];
    const float* W1 = (const float*)d_in[3];
    const float* b1 = (const float*)d_in[4];
    const float* W2 = (const float*)d_in[5];
    const float* b2 = (const float*)d_in[6];
    float* out = (float*)d_out;

    const int N = in_sizes[0] / CH_IN;         // 50000 (< 65536: 16-bit packing valid)
    const int E = in_sizes[2];
    const int NBK = (N + 255) >> 8;            // buckets of 256 nodes (196)
    const int EPB = (E + NBLK1 - 1) / NBLK1;   // edges per count/scatter block

    // workspace carve (float units; uint2/int2 8B-aligned, bf16 arrays 16B-aligned)
    float* ws0   = (float*)d_ws;
    float* ws    = ws0;
    float* dinv  = ws;               ws += N;
    int*   rowptr= (int*)ws;         ws += (N + 2);
    int*   cnt_bk= (int*)ws;         ws += 256 * NBLK1;
    int*   off_bk= (int*)ws;         ws += 256 * NBLK1;
    int*   btot  = (int*)ws;         ws += 256;
    uint2* ebuck = (uint2*)ws;       ws += (size_t)2 * E;
    int2*  epack = (int2*)ws;        ws += (size_t)2 * E;
    { size_t off = (size_t)(ws - ws0) & 3; if (off) ws += 4 - off; }   // 16B align
    unsigned short* h1   = (unsigned short*)ws;  ws += (size_t)N * CH_HID / 2;
    unsigned short* out1 = (unsigned short*)ws;  ws += (size_t)N * CH_HID / 2;
    unsigned short* h2   = (unsigned short*)ws;  ws += (size_t)N * CH_OUT / 2;

    const int B = 256;

    // 1) bucket count (atomic-free, LDS histograms)
    k_count<<<NBLK1, B, 0, stream>>>(ei, cnt_bk, E, NBK, EPB);

    // 2) per-bucket cross-block scan
    k_bscan<<<NBK, 256, 0, stream>>>(cnt_bk, off_bk, btot);

    // 3) GEMM1 co-scheduled with bucket scatter (longest build stage hidden)
    {
        const int nbg = (N + 63) / 64;
        k_fat<<<nbg + NBLK1, B, 0, stream>>>(x, W1, h1, N, nbg,
                                             ei, w, btot, off_bk, ebuck, E, NBK, EPB);
    }

    // 4) per-bucket CSR + dinv + final epack
    k_csr<<<NBK, 256, 0, stream>>>(ebuck, btot, rowptr, dinv, epack, N, NBK);

    // 5) out1 = b1 + self + neighbor aggregate
    k_agg128<<<(N * 64 + B - 1) / B, B, 0, stream>>>(rowptr, epack, dinv, h1, b1, out1, N);

    // 6) h2 = relu(out1) @ W2 (in-LDS W2 transpose)
    k_gemm_mfma<CH_OUT, true, unsigned short><<<(N + 63) / 64, 256, 0, stream>>>(out1, W2, h2, N);

    // 7) out = log_softmax(b2 + self + aggregate), fused, fp32 into d_out
    k_agg64<<<(N * 64 + B - 1) / B, B, 0, stream>>>(rowptr, epack, dinv, h2, b2, out, N);
}